// Round 8
// baseline (159.415 us; speedup 1.0000x reference)
//
#include <hip/hip_runtime.h>

#define G    128
#define G3   (G * G * G)          // 2097152
#define TDIM 32
#define NTOT (TDIM * G3)          // 67108864
#define NBYTES_OUT (NTOT / 8)     // 8388608
#define DECAY 0.95f
#define DTH   0.01f
#define NBLK  (TDIM * 256)        // 8192 blocks: one (t, 8x8x128 slab) each

typedef float f32x4 __attribute__((ext_vector_type(4)));
typedef float f32x2 __attribute__((ext_vector_type(2)));

// instant-ngp style bit expansion (<=10-bit inputs)
__device__ __forceinline__ unsigned expand3(unsigned v) {
    v = (v * 0x00010001u) & 0xFF0000FFu;
    v = (v * 0x00000101u) & 0x0F00F00Fu;
    v = (v * 0x00000011u) & 0xC30C30C3u;
    v = (v * 0x00000005u) & 0x49249249u;
    return v;
}

// LDS swizzle (pure function of slab-linear float index f = x<<10 | y<<7 | z):
// inject x1 (bit11) -> bank bit 2, y1 (bit8) -> bank bit 3, x2 (bit12) -> bank bit 4.
// Phase-A b128 writes: swizzle inputs wave-uniform -> linear conflict-free.
// Phase-B b32 reads: 32 distinct banks per half-wave, i/i+32 alias 2-way (free, m136).
__device__ __forceinline__ int swz(int f) {
    return f ^ ((((f >> 11) & 1) << 2) | (((f >> 8) & 1) << 3) | (((f >> 12) & 1) << 4));
}

__device__ __forceinline__ f32x4 merge4(f32x4 v, f32x4 s) {
    f32x4 r;
    r.x = (v.x >= 0.f && s.x >= 0.f) ? fmaxf(v.x * DECAY, s.x) : v.x;
    r.y = (v.y >= 0.f && s.y >= 0.f) ? fmaxf(v.y * DECAY, s.y) : v.y;
    r.z = (v.z >= 0.f && s.z >= 0.f) ? fmaxf(v.z * DECAY, s.z) : v.z;
    r.w = (v.w >= 0.f && s.w >= 0.f) ? fmaxf(v.w * DECAY, s.w) : v.w;
    return r;
}

// One block = one (t, 8x8x128 slab). Wave = 2 runs (8x8x8 subcubes) = 1024 morton floats.
// Lane i owns float4s {i, i+64, i+128, i+192} of the wave region -> every global
// load/store is a contiguous 1024B wave transaction. Sigma loads issued FIRST
// (they feed the pre-barrier LDS phase); density loads second (needed post-barrier).
// Plain cached accesses (R3 post-mortem: nt defeats L3 retention across replays).
// Mean-reduction fused via one atomicAdd per block (fp order nondeterminism is
// harmless: thresh = min(mean~0.28, 0.01) = 0.01 regardless of rounding).
__global__ __launch_bounds__(512, 8) void
pass1(const float* __restrict__ dg, const float* __restrict__ sg,
      float* __restrict__ out_grid, float* __restrict__ out_bits,
      float* __restrict__ sum_acc)
{
    __shared__ float smem[8192];          // 32 KB
    __shared__ float wsum[8];
    const int blk  = blockIdx.x;          // t*256 + slab
    const int t    = blk >> 8;
    const int pp   = blk & 255;
    const int sx   = pp & 15;             // slab x (x = 8*sx + lx)
    const int sy   = pp >> 4;             // slab y
    const int base = t * G3;
    const int tid  = threadIdx.x;
    const int w    = tid >> 6;            // wave 0..7 -> runs 2w, 2w+1
    const int i    = tid & 63;            // lane

    // ---- Phase A loads FIRST (critical path: feed LDS before barrier) ----
    const float* __restrict__ sgt = sg + base + (sx << 17) + (sy << 10);
    f32x4 sa0, sa1, sa2, sa3;
    {
        const int x0 = tid >> 8,          rem0 = tid & 255;
        const int x1 = (tid + 512) >> 8,  rem1 = tid & 255;
        const int x2 = (tid + 1024) >> 8, rem2 = tid & 255;
        const int x3 = (tid + 1536) >> 8, rem3 = tid & 255;
        sa0 = *reinterpret_cast<const f32x4*>(sgt + (x0 << 14) + (rem0 << 2));
        sa1 = *reinterpret_cast<const f32x4*>(sgt + (x1 << 14) + (rem1 << 2));
        sa2 = *reinterpret_cast<const f32x4*>(sgt + (x2 << 14) + (rem2 << 2));
        sa3 = *reinterpret_cast<const f32x4*>(sgt + (x3 << 14) + (rem3 << 2));
    }

    // ---- density loads second: 4x 1024B wave transactions, needed after barrier ----
    const int m_fixed = (int)((expand3((unsigned)sx) << 9) | (expand3((unsigned)sy) << 10));
    const int jgA = base + m_fixed + ((int)expand3((unsigned)w) << 14) + (i << 2);
    const f32x4* dgp = reinterpret_cast<const f32x4*>(dg + jgA);
    const f32x4 v0 = dgp[0];     // run A, float4 #i
    const f32x4 v1 = dgp[64];    // run A, float4 #(64+i)
    const f32x4 v2 = dgp[512];   // run B, float4 #i
    const f32x4 v3 = dgp[576];   // run B, float4 #(64+i)

    // ---- Phase A writes: LDS slab-linear b128, conflict-free ----
    {
        const int f0 = swz(((tid >> 8) << 10)          + ((tid & 255) << 2));
        const int f1 = swz((((tid + 512) >> 8) << 10)  + ((tid & 255) << 2));
        const int f2 = swz((((tid + 1024) >> 8) << 10) + ((tid & 255) << 2));
        const int f3 = swz((((tid + 1536) >> 8) << 10) + ((tid & 255) << 2));
        *reinterpret_cast<f32x4*>(&smem[f0]) = sa0;
        *reinterpret_cast<f32x4*>(&smem[f1]) = sa1;
        *reinterpret_cast<f32x4*>(&smem[f2]) = sa2;
        *reinterpret_cast<f32x4*>(&smem[f3]) = sa3;
    }
    __syncthreads();

    // ---- Phase B: 16x ds_read_b32 (swizzled) -> 4 morton float4s ----
    // float4 #n (n = 64*(c&1) + i) of run r: morton m=4n ->
    //   f = z0 | z1<<1 | z2<<2 | r<<3 | y1<<8 | y2<<9 | x1<<11 | x2<<12
    //   4 floats at f, f+1024 (x0), f+128 (y0), f+1152
    const int fi = (i & 1) | (((i >> 3) & 1) << 1) | (((i >> 2) & 1) << 8)
                 | (((i >> 5) & 1) << 9) | (((i >> 1) & 1) << 11) | (((i >> 4) & 1) << 12);
    const int S  = (((fi >> 11) & 1) << 2) | (((fi >> 8) & 1) << 3) | (((fi >> 12) & 1) << 4);
    const int A  = w << 4;                          // run bits
    const float* sp0 = &smem[fi | ((A + 0)  ^ S)];  // c0: run A, z2=0
    const float* sp1 = &smem[fi | ((A + 4)  ^ S)];  // c1: run A, z2=1
    const float* sp2 = &smem[fi | ((A + 8)  ^ S)];  // c2: run B, z2=0
    const float* sp3 = &smem[fi | ((A + 12) ^ S)];  // c3: run B, z2=1
    f32x4 s0; s0.x = sp0[0]; s0.y = sp0[1024]; s0.z = sp0[128]; s0.w = sp0[1152];
    f32x4 s1; s1.x = sp1[0]; s1.y = sp1[1024]; s1.z = sp1[128]; s1.w = sp1[1152];
    f32x4 s2; s2.x = sp2[0]; s2.y = sp2[1024]; s2.z = sp2[128]; s2.w = sp2[1152];
    f32x4 s3; s3.x = sp3[0]; s3.y = sp3[1024]; s3.z = sp3[128]; s3.w = sp3[1152];

    const f32x4 r0 = merge4(v0, s0);
    const f32x4 r1 = merge4(v1, s1);
    const f32x4 r2 = merge4(v2, s2);
    const f32x4 r3 = merge4(v3, s3);

    // ---- grid stores: 4x 1024B wave transactions ----
    f32x4* ogp = reinterpret_cast<f32x4*>(out_grid + jgA);
    ogp[0]   = r0;
    ogp[64]  = r1;
    ogp[512] = r2;
    ogp[576] = r3;

    float lsum = fmaxf(r0.x, 0.f) + fmaxf(r0.y, 0.f) + fmaxf(r0.z, 0.f) + fmaxf(r0.w, 0.f)
               + fmaxf(r1.x, 0.f) + fmaxf(r1.y, 0.f) + fmaxf(r1.z, 0.f) + fmaxf(r1.w, 0.f)
               + fmaxf(r2.x, 0.f) + fmaxf(r2.y, 0.f) + fmaxf(r2.z, 0.f) + fmaxf(r2.w, 0.f)
               + fmaxf(r3.x, 0.f) + fmaxf(r3.y, 0.f) + fmaxf(r3.z, 0.f) + fmaxf(r3.w, 0.f);

    // ---- bitfield: nibble per chunk, pair-merge via shfl_xor, even lanes store ----
    int n0 = (r0.x > DTH ? 1 : 0) | (r0.y > DTH ? 2 : 0) | (r0.z > DTH ? 4 : 0) | (r0.w > DTH ? 8 : 0);
    int n1 = (r1.x > DTH ? 1 : 0) | (r1.y > DTH ? 2 : 0) | (r1.z > DTH ? 4 : 0) | (r1.w > DTH ? 8 : 0);
    int n2 = (r2.x > DTH ? 1 : 0) | (r2.y > DTH ? 2 : 0) | (r2.z > DTH ? 4 : 0) | (r2.w > DTH ? 8 : 0);
    int n3 = (r3.x > DTH ? 1 : 0) | (r3.y > DTH ? 2 : 0) | (r3.z > DTH ? 4 : 0) | (r3.w > DTH ? 8 : 0);
    const int p0 = __shfl_xor(n0, 1, 64);
    const int p1 = __shfl_xor(n1, 1, 64);
    const int p2 = __shfl_xor(n2, 1, 64);
    const int p3 = __shfl_xor(n3, 1, 64);
    if ((i & 1) == 0) {
        float* bp = out_bits + (jgA >> 3);
        bp[0]   = (float)(n0 | (p0 << 4));
        bp[32]  = (float)(n1 | (p1 << 4));
        bp[256] = (float)(n2 | (p2 << 4));
        bp[288] = (float)(n3 | (p3 << 4));
    }

    // ---- fused mean-reduction: block reduce + one atomicAdd ----
    #pragma unroll
    for (int offl = 32; offl; offl >>= 1) lsum += __shfl_down(lsum, offl, 64);
    if ((tid & 63) == 0) wsum[tid >> 6] = lsum;
    __syncthreads();
    if (tid == 0) {
        float tot = 0.f;
        #pragma unroll
        for (int k = 0; k < 8; ++k) tot += wsum[k];
        atomicAdd(sum_acc, tot);
    }
}

// Fallback: recompute bits iff mean < DTH (never for this data). Early-exits otherwise.
__global__ __launch_bounds__(256) void
fix_bits(const float* __restrict__ grid, const float* __restrict__ sum_acc,
         float* __restrict__ out_bits)
{
    const float th = fminf(sum_acc[0] / (float)NTOT, DTH);
    if (th == DTH) return;                        // common case: nothing to do
    for (int n = blockIdx.x * 256 + threadIdx.x; n < NBYTES_OUT; n += 256 * 1024) {
        const float4* g = reinterpret_cast<const float4*>(grid) + (n << 1);
        const float4 a = g[0], b = g[1];
        int byte = (a.x > th ? 1 : 0)   | (a.y > th ? 2 : 0)   |
                   (a.z > th ? 4 : 0)   | (a.w > th ? 8 : 0)   |
                   (b.x > th ? 16 : 0)  | (b.y > th ? 32 : 0)  |
                   (b.z > th ? 64 : 0)  | (b.w > th ? 128 : 0);
        out_bits[n] = (float)byte;
    }
}

extern "C" void kernel_launch(void* const* d_in, const int* in_sizes, int n_in,
                              void* d_out, int out_size, void* d_ws, size_t ws_size,
                              hipStream_t stream)
{
    const float* dg = (const float*)d_in[0];   // density_grid [T,1,G^3]
    const float* sg = (const float*)d_in[1];   // sigmas       [T,1,G^3]
    float* out_grid = (float*)d_out;           // [T,1,G^3]
    float* out_bits = out_grid + NTOT;         // [T, G^3/8] as float values
    float* sum_acc  = (float*)d_ws;            // 1 float accumulator

    hipMemsetAsync(sum_acc, 0, sizeof(float), stream);
    pass1<<<NBLK, 512, 0, stream>>>(dg, sg, out_grid, out_bits, sum_acc);
    fix_bits<<<1024, 256, 0, stream>>>(out_grid, sum_acc, out_bits);
}

// Round 9
// 155.044 us; speedup vs baseline: 1.0282x; 1.0282x over previous
//
#include <hip/hip_runtime.h>

#define G    128
#define G3   (G * G * G)          // 2097152
#define TDIM 32
#define NTOT (TDIM * G3)          // 67108864
#define NBYTES_OUT (NTOT / 8)     // 8388608
#define DECAY 0.95f
#define DTH   0.01f
#define NBLK  (TDIM * 256)        // 8192 blocks: one (t, 8x8x128 slab) each

typedef float f32x4 __attribute__((ext_vector_type(4)));
typedef float f32x2 __attribute__((ext_vector_type(2)));

// instant-ngp style bit expansion (<=10-bit inputs)
__device__ __forceinline__ unsigned expand3(unsigned v) {
    v = (v * 0x00010001u) & 0xFF0000FFu;
    v = (v * 0x00000101u) & 0x0F00F00Fu;
    v = (v * 0x00000011u) & 0xC30C30C3u;
    v = (v * 0x00000005u) & 0x49249249u;
    return v;
}

// LDS swizzle (pure function of slab-linear float index f = x<<10 | y<<7 | z):
// inject x1 (bit11) -> bank bit 2, y1 (bit8) -> bank bit 3, x2 (bit12) -> bank bit 4.
// Phase-A b128 writes stay linear conflict-free (swizzle inputs wave-uniform);
// Phase-B b32 reads: 32 distinct banks per half-wave, i/i+32 alias 2-way (free, m136).
__device__ __forceinline__ int swz(int f) {
    return f ^ ((((f >> 11) & 1) << 2) | (((f >> 8) & 1) << 3) | (((f >> 12) & 1) << 4));
}

__device__ __forceinline__ f32x4 merge4(f32x4 v, f32x4 s) {
    f32x4 r;
    r.x = (v.x >= 0.f && s.x >= 0.f) ? fmaxf(v.x * DECAY, s.x) : v.x;
    r.y = (v.y >= 0.f && s.y >= 0.f) ? fmaxf(v.y * DECAY, s.y) : v.y;
    r.z = (v.z >= 0.f && s.z >= 0.f) ? fmaxf(v.z * DECAY, s.z) : v.z;
    r.w = (v.w >= 0.f && s.w >= 0.f) ? fmaxf(v.w * DECAY, s.w) : v.w;
    return r;
}

// One block = one (t, 8x8x128 slab). Wave = 2 runs (8x8x8 subcubes) = 1024 morton floats.
// Lane i owns float4s {i, i+64, i+128, i+192} of the wave region -> every global
// load/store is a contiguous 1024B wave transaction.
// L3-retention steering (R8 post-mortem): sigma loads are NON-TEMPORAL (no L3
// alloc) so density_grid (268 MB ~= L3 capacity) becomes the sole resident
// stream -> dg reads ~all L3 hits, sigma misses are perfectly-sequential HBM
// streams (DRAM row locality), instead of a scattered ~50% miss pattern on both.
// Stores stay plain (R3: nt stores inflated WRITE_SIZE +145 MB).
__global__ __launch_bounds__(512, 8) void
pass1(const float* __restrict__ dg, const float* __restrict__ sg,
      float* __restrict__ out_grid, float* __restrict__ out_bits,
      float* __restrict__ sum_acc)
{
    __shared__ float smem[8192];          // 32 KB
    __shared__ float wsum[8];
    const int blk  = blockIdx.x;          // t*256 + slab
    const int t    = blk >> 8;
    const int pp   = blk & 255;
    const int sx   = pp & 15;             // slab x (x = 8*sx + lx)
    const int sy   = pp >> 4;             // slab y
    const int base = t * G3;
    const int tid  = threadIdx.x;
    const int w    = tid >> 6;            // wave 0..7 -> runs 2w, 2w+1
    const int i    = tid & 63;            // lane

    // ---- Phase A loads FIRST (critical path: feed LDS before barrier) ----
    const float* __restrict__ sgt = sg + base + (sx << 17) + (sy << 10);
    f32x4 sa0, sa1, sa2, sa3;
    {
        const int rem = (tid & 255) << 2;
        sa0 = __builtin_nontemporal_load(
                reinterpret_cast<const f32x4*>(sgt + ((tid >> 8) << 14)          + rem));
        sa1 = __builtin_nontemporal_load(
                reinterpret_cast<const f32x4*>(sgt + (((tid + 512) >> 8) << 14)  + rem));
        sa2 = __builtin_nontemporal_load(
                reinterpret_cast<const f32x4*>(sgt + (((tid + 1024) >> 8) << 14) + rem));
        sa3 = __builtin_nontemporal_load(
                reinterpret_cast<const f32x4*>(sgt + (((tid + 1536) >> 8) << 14) + rem));
    }

    // ---- density loads second (plain/cached -> L3-resident across replays) ----
    const int m_fixed = (int)((expand3((unsigned)sx) << 9) | (expand3((unsigned)sy) << 10));
    const int jgA = base + m_fixed + ((int)expand3((unsigned)w) << 14) + (i << 2);
    const f32x4* dgp = reinterpret_cast<const f32x4*>(dg + jgA);
    const f32x4 v0 = dgp[0];     // run A, float4 #i
    const f32x4 v1 = dgp[64];    // run A, float4 #(64+i)
    const f32x4 v2 = dgp[512];   // run B, float4 #i
    const f32x4 v3 = dgp[576];   // run B, float4 #(64+i)

    // ---- Phase A writes: LDS slab-linear b128, conflict-free ----
    {
        const int rem = (tid & 255) << 2;
        *reinterpret_cast<f32x4*>(&smem[swz(((tid >> 8) << 10)          + rem)]) = sa0;
        *reinterpret_cast<f32x4*>(&smem[swz((((tid + 512) >> 8) << 10)  + rem)]) = sa1;
        *reinterpret_cast<f32x4*>(&smem[swz((((tid + 1024) >> 8) << 10) + rem)]) = sa2;
        *reinterpret_cast<f32x4*>(&smem[swz((((tid + 1536) >> 8) << 10) + rem)]) = sa3;
    }
    __syncthreads();

    // ---- Phase B: 16x ds_read_b32 (swizzled) -> 4 morton float4s ----
    // float4 #n (n = 64*(c&1) + i) of run r: morton m=4n ->
    //   f = z0 | z1<<1 | z2<<2 | r<<3 | y1<<8 | y2<<9 | x1<<11 | x2<<12
    //   4 floats at f, f+1024 (x0), f+128 (y0), f+1152
    const int fi = (i & 1) | (((i >> 3) & 1) << 1) | (((i >> 2) & 1) << 8)
                 | (((i >> 5) & 1) << 9) | (((i >> 1) & 1) << 11) | (((i >> 4) & 1) << 12);
    const int S  = (((fi >> 11) & 1) << 2) | (((fi >> 8) & 1) << 3) | (((fi >> 12) & 1) << 4);
    const int A  = w << 4;                          // run bits
    const float* sp0 = &smem[fi | ((A + 0)  ^ S)];  // c0: run A, z2=0
    const float* sp1 = &smem[fi | ((A + 4)  ^ S)];  // c1: run A, z2=1
    const float* sp2 = &smem[fi | ((A + 8)  ^ S)];  // c2: run B, z2=0
    const float* sp3 = &smem[fi | ((A + 12) ^ S)];  // c3: run B, z2=1
    f32x4 s0; s0.x = sp0[0]; s0.y = sp0[1024]; s0.z = sp0[128]; s0.w = sp0[1152];
    f32x4 s1; s1.x = sp1[0]; s1.y = sp1[1024]; s1.z = sp1[128]; s1.w = sp1[1152];
    f32x4 s2; s2.x = sp2[0]; s2.y = sp2[1024]; s2.z = sp2[128]; s2.w = sp2[1152];
    f32x4 s3; s3.x = sp3[0]; s3.y = sp3[1024]; s3.z = sp3[128]; s3.w = sp3[1152];

    const f32x4 r0 = merge4(v0, s0);
    const f32x4 r1 = merge4(v1, s1);
    const f32x4 r2 = merge4(v2, s2);
    const f32x4 r3 = merge4(v3, s3);

    // ---- grid stores: 4x 1024B wave transactions (plain) ----
    f32x4* ogp = reinterpret_cast<f32x4*>(out_grid + jgA);
    ogp[0]   = r0;
    ogp[64]  = r1;
    ogp[512] = r2;
    ogp[576] = r3;

    float lsum = fmaxf(r0.x, 0.f) + fmaxf(r0.y, 0.f) + fmaxf(r0.z, 0.f) + fmaxf(r0.w, 0.f)
               + fmaxf(r1.x, 0.f) + fmaxf(r1.y, 0.f) + fmaxf(r1.z, 0.f) + fmaxf(r1.w, 0.f)
               + fmaxf(r2.x, 0.f) + fmaxf(r2.y, 0.f) + fmaxf(r2.z, 0.f) + fmaxf(r2.w, 0.f)
               + fmaxf(r3.x, 0.f) + fmaxf(r3.y, 0.f) + fmaxf(r3.z, 0.f) + fmaxf(r3.w, 0.f);

    // ---- bitfield: nibble per chunk, pair-merge via shfl_xor, even lanes store ----
    int n0 = (r0.x > DTH ? 1 : 0) | (r0.y > DTH ? 2 : 0) | (r0.z > DTH ? 4 : 0) | (r0.w > DTH ? 8 : 0);
    int n1 = (r1.x > DTH ? 1 : 0) | (r1.y > DTH ? 2 : 0) | (r1.z > DTH ? 4 : 0) | (r1.w > DTH ? 8 : 0);
    int n2 = (r2.x > DTH ? 1 : 0) | (r2.y > DTH ? 2 : 0) | (r2.z > DTH ? 4 : 0) | (r2.w > DTH ? 8 : 0);
    int n3 = (r3.x > DTH ? 1 : 0) | (r3.y > DTH ? 2 : 0) | (r3.z > DTH ? 4 : 0) | (r3.w > DTH ? 8 : 0);
    const int p0 = __shfl_xor(n0, 1, 64);
    const int p1 = __shfl_xor(n1, 1, 64);
    const int p2 = __shfl_xor(n2, 1, 64);
    const int p3 = __shfl_xor(n3, 1, 64);
    if ((i & 1) == 0) {
        float* bp = out_bits + (jgA >> 3);
        bp[0]   = (float)(n0 | (p0 << 4));
        bp[32]  = (float)(n1 | (p1 << 4));
        bp[256] = (float)(n2 | (p2 << 4));
        bp[288] = (float)(n3 | (p3 << 4));
    }

    // ---- fused mean-reduction: block reduce + one atomicAdd ----
    #pragma unroll
    for (int offl = 32; offl; offl >>= 1) lsum += __shfl_down(lsum, offl, 64);
    if ((tid & 63) == 0) wsum[tid >> 6] = lsum;
    __syncthreads();
    if (tid == 0) {
        float tot = 0.f;
        #pragma unroll
        for (int k = 0; k < 8; ++k) tot += wsum[k];
        atomicAdd(sum_acc, tot);
    }
}

// Fallback: recompute bits iff mean < DTH (never for this data). Early-exits otherwise.
__global__ __launch_bounds__(256) void
fix_bits(const float* __restrict__ grid, const float* __restrict__ sum_acc,
         float* __restrict__ out_bits)
{
    const float th = fminf(sum_acc[0] / (float)NTOT, DTH);
    if (th == DTH) return;                        // common case: nothing to do
    for (int n = blockIdx.x * 256 + threadIdx.x; n < NBYTES_OUT; n += 256 * 1024) {
        const float4* g = reinterpret_cast<const float4*>(grid) + (n << 1);
        const float4 a = g[0], b = g[1];
        int byte = (a.x > th ? 1 : 0)   | (a.y > th ? 2 : 0)   |
                   (a.z > th ? 4 : 0)   | (a.w > th ? 8 : 0)   |
                   (b.x > th ? 16 : 0)  | (b.y > th ? 32 : 0)  |
                   (b.z > th ? 64 : 0)  | (b.w > th ? 128 : 0);
        out_bits[n] = (float)byte;
    }
}

extern "C" void kernel_launch(void* const* d_in, const int* in_sizes, int n_in,
                              void* d_out, int out_size, void* d_ws, size_t ws_size,
                              hipStream_t stream)
{
    const float* dg = (const float*)d_in[0];   // density_grid [T,1,G^3]
    const float* sg = (const float*)d_in[1];   // sigmas       [T,1,G^3]
    float* out_grid = (float*)d_out;           // [T,1,G^3]
    float* out_bits = out_grid + NTOT;         // [T, G^3/8] as float values
    float* sum_acc  = (float*)d_ws;            // 1 float accumulator

    hipMemsetAsync(sum_acc, 0, sizeof(float), stream);
    pass1<<<NBLK, 512, 0, stream>>>(dg, sg, out_grid, out_bits, sum_acc);
    fix_bits<<<1024, 256, 0, stream>>>(out_grid, sum_acc, out_bits);
}